// Round 3
// baseline (385.132 us; speedup 1.0000x reference)
//
#include <hip/hip_runtime.h>

#define NB_ 32
#define NP_ 65536
#define NT_ 16
#define HB 1024
#define HSCALE 128.0f
#define NBX 64     // kernel1 blocks per batch (1024 priors each)

__device__ __forceinline__ float softplus_(float x) {
    // log(1 + e^x), stable
    return fmaxf(x, 0.0f) + __logf(1.0f + __expf(-fabsf(x)));
}

__device__ __forceinline__ float iou_fast(float tx0, float ty0, float tx1, float ty1, float ta,
                                          float bx0, float by0, float bx1, float by1, float ar) {
    float lx = fmaxf(tx0, bx0), ly = fmaxf(ty0, by0);
    float rx = fminf(tx1, bx1), ry = fminf(ty1, by1);
    float w = fmaxf(rx - lx, 0.0f), h = fmaxf(ry - ly, 0.0f);
    float inter = w * h;
    return __fdividef(inter, ta + ar - inter);
}

// ---- DPP wave64 reductions (result valid in lane 63) ----
#define DPP_STEP(x, t, ctrl, rmask, bmask, OP)                                          \
    t = __builtin_amdgcn_update_dpp(0, (x), (ctrl), (rmask), (bmask), true); OP;

__device__ __forceinline__ unsigned wave_max_u32(unsigned v) {
    int x = (int)v, t;
    DPP_STEP(x, t, 0x111, 0xf, 0xf, x = ((unsigned)t > (unsigned)x) ? t : x)
    DPP_STEP(x, t, 0x112, 0xf, 0xf, x = ((unsigned)t > (unsigned)x) ? t : x)
    DPP_STEP(x, t, 0x114, 0xf, 0xe, x = ((unsigned)t > (unsigned)x) ? t : x)
    DPP_STEP(x, t, 0x118, 0xf, 0xc, x = ((unsigned)t > (unsigned)x) ? t : x)
    DPP_STEP(x, t, 0x142, 0xa, 0xf, x = ((unsigned)t > (unsigned)x) ? t : x)
    DPP_STEP(x, t, 0x143, 0xc, 0xf, x = ((unsigned)t > (unsigned)x) ? t : x)
    return (unsigned)x;
}

__device__ __forceinline__ float wave_sum_f32(float v) {
    int x = __float_as_int(v), t;
    float f;
    DPP_STEP(x, t, 0x111, 0xf, 0xf, f = __int_as_float(x) + __int_as_float(t); x = __float_as_int(f))
    DPP_STEP(x, t, 0x112, 0xf, 0xf, f = __int_as_float(x) + __int_as_float(t); x = __float_as_int(f))
    DPP_STEP(x, t, 0x114, 0xf, 0xe, f = __int_as_float(x) + __int_as_float(t); x = __float_as_int(f))
    DPP_STEP(x, t, 0x118, 0xf, 0xc, f = __int_as_float(x) + __int_as_float(t); x = __float_as_int(f))
    DPP_STEP(x, t, 0x142, 0xa, 0xf, f = __int_as_float(x) + __int_as_float(t); x = __float_as_int(f))
    DPP_STEP(x, t, 0x143, 0xc, 0xf, f = __int_as_float(x) + __int_as_float(t); x = __float_as_int(f))
    return __int_as_float(x);
}

__device__ __forceinline__ int wave_sum_i32(int v) {
    int x = v, t;
    DPP_STEP(x, t, 0x111, 0xf, 0xf, x = x + t)
    DPP_STEP(x, t, 0x112, 0xf, 0xf, x = x + t)
    DPP_STEP(x, t, 0x114, 0xf, 0xe, x = x + t)
    DPP_STEP(x, t, 0x118, 0xf, 0xc, x = x + t)
    DPP_STEP(x, t, 0x142, 0xa, 0xf, x = x + t)
    DPP_STEP(x, t, 0x143, 0xc, 0xf, x = x + t)
    return x;
}

// R9: single-kernel design. Per-batch ticket elects the 64th-completing block
// of each batch as that batch's finisher (hist merge + fixup + selection),
// overlapping finish work with other batches' main compute. A global ticket
// elects the final cross-batch reducer. Removes the finishK dispatch and the
// full inter-kernel drain. Tickets are zeroed by a 256 B hipMemsetAsync before
// launch (in-kernel init would race). Visibility uses the release-fence ->
// device atomic -> acquire-fence pattern already validated by the old finishK.
__global__ void __launch_bounds__(256) mainK(
    const float* __restrict__ loc, const float* __restrict__ conf,
    const float* __restrict__ priors, const float* __restrict__ targets,
    unsigned short* __restrict__ gcnt, float* __restrict__ gsum,
    unsigned long long* __restrict__ bestPart,
    float* __restrict__ part_ll, float* __restrict__ part_pc, int* __restrict__ part_np,
    float* __restrict__ final_l, float* __restrict__ final_c, int* __restrict__ final_n,
    unsigned* __restrict__ ticketB, unsigned* __restrict__ ticket2,
    float* __restrict__ out)
{
    const int bx = blockIdx.x, b = blockIdx.y, tid = threadIdx.x;

    __shared__ float4 trb[NT_];   // x0,y0,x1,y1
    __shared__ float tra[NT_];    // area
    __shared__ int hc[HB];
    __shared__ float hs[HB];
    __shared__ unsigned wkey[4][NT_], wp[4][NT_];
    __shared__ float sh_ll[4], sh_pc[4];
    __shared__ int sh_np[4];
    // finisher-phase shared state
    __shared__ unsigned s_old;
    __shared__ unsigned ps[NT_];
    __shared__ float s_dll, s_dpc, s_sll, s_spc;
    __shared__ int s_dnp, s_sn, s_last;
    __shared__ unsigned ccnt[16];
    __shared__ float csm[16];

    for (int i = tid; i < HB; i += 256) { hc[i] = 0; hs[i] = 0.0f; }
    if (tid < NT_) {
        const float* tp = targets + ((size_t)b * NT_ + tid) * 5;
        float x0 = tp[0], y0 = tp[1], x1 = tp[2], y1 = tp[3];
        trb[tid] = make_float4(x0, y0, x1, y1);
        tra[tid] = (x1 - x0) * (y1 - y0);
    }
    __syncthreads();

    const int pbase = bx * 1024 + tid;
    float pbx0[4], pby0[4], pbx1[4], pby1[4], par[4];
    float2 cxy[4];
#pragma unroll
    for (int i = 0; i < 4; i++) {
        float4 pr = ((const float4*)priors)[pbase + 256 * i];
        cxy[i] = ((const float2*)conf)[(size_t)b * NP_ + pbase + 256 * i];  // in flight during t-loop
        float hw = pr.z * 0.5f, hh = pr.w * 0.5f;
        pbx0[i] = pr.x - hw; pby0[i] = pr.y - hh;
        pbx1[i] = pr.x + hw; pby1[i] = pr.y + hh;
        par[i] = (pbx1[i] - pbx0[i]) * (pby1[i] - pby0[i]);
    }

    unsigned pkey[4] = {0u, 0u, 0u, 0u};  // per-prior best (iou_key | (15-t))
    unsigned tkey[NT_];                   // per-truth best (iou_key | (15-i))
#pragma unroll
    for (int t = 0; t < NT_; t++) tkey[t] = 0u;

#pragma unroll
    for (int t = 0; t < NT_; t++) {
        float4 tb = trb[t];          // ds_read_b128 (broadcast)
        float ta = tra[t];           // ds_read_b32
#pragma unroll
        for (int i = 0; i < 4; i++) {
            float iou = iou_fast(tb.x, tb.y, tb.z, tb.w, ta,
                                 pbx0[i], pby0[i], pbx1[i], pby1[i], par[i]);
            // monotone u32 key; 2 LSB mantissa bits -> 4-bit tie-break index
            // (ties prefer smaller t / smaller prior index)
            unsigned base = (__float_as_uint(iou) & 0xFFFFFFFCu) << 2;
            unsigned kt = base | (unsigned)(15 - t);
            unsigned kp = base | (unsigned)(15 - i);
            pkey[i] = (kt > pkey[i]) ? kt : pkey[i];
            tkey[t] = (kp > tkey[t]) ? kp : tkey[t];
        }
    }

    float ll_acc = 0.0f, pc_acc = 0.0f;
    int np_acc = 0;
#pragma unroll
    for (int i = 0; i < 4; i++) {
        int p = pbase + 256 * i;
        size_t bp = (size_t)b * NP_ + p;
        bool pos = (pkey[i] >= 0xFC000000u);  // iou >= 0.5 (0.5 has zero low bits)
        float dd = cxy[i].y - cxy[i].x;
        float v = pos ? 0.0f : softplus_(dd);  // loss_c_mine
        int bin = min(HB - 1, (int)(v * HSCALE));
        atomicAdd(&hc[bin], 1);
        atomicAdd(&hs[bin], v);
        if (pos) {
            np_acc++;
            pc_acc += softplus_(-dd);  // lse - c.y
            int t = 15 - (int)(pkey[i] & 15u);
            float4 tb = trb[t];
            float4 prv = ((const float4*)priors)[p];  // reload: same bits as staging load
            float gcx = ((tb.x + tb.z) * 0.5f - prv.x) / (0.1f * prv.z);
            float gcy = ((tb.y + tb.w) * 0.5f - prv.y) / (0.1f * prv.w);
            float gw = __logf((tb.z - tb.x) / prv.z) * 5.0f;
            float gh = __logf((tb.w - tb.y) / prv.w) * 5.0f;
            float4 ld = ((const float4*)loc)[bp];
            float d0 = fabsf(ld.x - gcx), d1 = fabsf(ld.y - gcy);
            float d2 = fabsf(ld.z - gw),  d3 = fabsf(ld.w - gh);
            ll_acc += (d0 < 1.0f) ? 0.5f * d0 * d0 : d0 - 0.5f;
            ll_acc += (d1 < 1.0f) ? 0.5f * d1 * d1 : d1 - 0.5f;
            ll_acc += (d2 < 1.0f) ? 0.5f * d2 * d2 : d2 - 0.5f;
            ll_acc += (d3 < 1.0f) ? 0.5f * d3 * d3 : d3 - 0.5f;
        }
    }

    // per-wave reductions — DPP chains (VALU), no LDS pipe
    const int wave = tid >> 6, lane = tid & 63;
#pragma unroll
    for (int t = 0; t < NT_; t++) {
        unsigned k = tkey[t];
        unsigned m = (unsigned)__builtin_amdgcn_readlane((int)wave_max_u32(k), 63);
        unsigned long long ball = __ballot(k == m);
        if (lane == 0) {
            int l = __ffsll((long long)ball) - 1;  // lowest lane = smallest p (same i)
            int ci = 15 - (int)(m & 15u);
            int p = bx * 1024 + ci * 256 + wave * 64 + l;
            wkey[wave][t] = m;
            wp[wave][t] = (unsigned)p;
        }
    }
    {
        float llw = wave_sum_f32(ll_acc);
        float pcw = wave_sum_f32(pc_acc);
        int npw = wave_sum_i32(np_acc);
        if (lane == 63) { sh_ll[wave] = llw; sh_pc[wave] = pcw; sh_np[wave] = npw; }
    }
    __syncthreads();

    if (tid < NT_) {
        unsigned bk = wkey[0][tid], bpv = wp[0][tid];
        for (int w = 1; w < 4; w++) {
            unsigned k2 = wkey[w][tid], p2 = wp[w][tid];
            if (k2 > bk || (k2 == bk && p2 < bpv)) { bk = k2; bpv = p2; }
        }
        unsigned long long pk = (((unsigned long long)bk) << 32) | (unsigned)(~bpv);
        bestPart[((size_t)b * NT_ + tid) * NBX + bx] = pk;   // plain store
    }
    if (tid == 0) {
        part_ll[b * NBX + bx] = sh_ll[0] + sh_ll[1] + sh_ll[2] + sh_ll[3];
        part_pc[b * NBX + bx] = sh_pc[0] + sh_pc[1] + sh_pc[2] + sh_pc[3];
        part_np[b * NBX + bx] = sh_np[0] + sh_np[1] + sh_np[2] + sh_np[3];
    }
    // deterministic per-block hist writeback (coalesced); counts fit u16 (<=1024)
    {
        unsigned short* gc = gcnt + ((size_t)(b * NBX + bx)) * HB;
        float* gs = gsum + ((size_t)(b * NBX + bx)) * HB;
        for (int i = tid; i < HB; i += 256) { gc[i] = (unsigned short)hc[i]; gs[i] = hs[i]; }
    }

    // ===== per-batch finisher election =====
    __threadfence();                         // release: all our ws stores
    if (tid == 0) s_old = atomicAdd(&ticketB[b], 1u);
    __syncthreads();
    if (s_old != NBX - 1) return;            // 63 of 64 blocks exit here

    __threadfence();                         // acquire: other blocks' ws stores

    // merge NBX per-block hists into LDS (reuse hc/hs); deterministic j-order
    if (tid == 0) { s_dll = 0.0f; s_dpc = 0.0f; s_dnp = 0; s_last = 0; }
    for (int i = tid; i < HB; i += 256) {
        int c = 0; float s = 0.0f;
#pragma unroll 8
        for (int j = 0; j < NBX; j++) {
            c += (int)gcnt[((size_t)(b * NBX + j)) * HB + i];
            s += gsum[((size_t)(b * NBX + j)) * HB + i];
        }
        hc[i] = c; hs[i] = s;
    }
    // merge per-truth best priors
    if (tid < NT_) {
        unsigned long long v = bestPart[((size_t)b * NT_ + tid) * NBX];
        for (int j = 1; j < NBX; j++) {
            unsigned long long u = bestPart[((size_t)b * NT_ + tid) * NBX + j];
            if (u > v) v = u;   // equal keys keep first j = smaller prior range
        }
        ps[tid] = ~((unsigned)(v & 0xffffffffULL));
    }
    // part sums: 64 lanes, fixed DPP tree (deterministic)
    if (tid < 64) {
        float lv = part_ll[b * NBX + tid];
        float pv = part_pc[b * NBX + tid];
        int nv = part_np[b * NBX + tid];
        lv = wave_sum_f32(lv); pv = wave_sum_f32(pv); nv = wave_sum_i32(nv);
        if (tid == 63) { s_sll = lv; s_spc = pv; s_sn = nv; }
    }
    __syncthreads();

    // fixup (16 threads) — adjustments into LDS; same math as old finishK
    if (tid < NT_) {
        unsigned p = ps[tid];
        bool active = true;
        for (int u = tid + 1; u < NT_; u++)
            if (ps[u] == p) { active = false; break; }  // last-wins dedup
        if (active) {
            float4 prv = ((const float4*)priors)[p];
            float hw = prv.z * 0.5f, hh = prv.w * 0.5f;
            float qx0 = prv.x - hw, qy0 = prv.y - hh;
            float qx1 = prv.x + hw, qy1 = prv.y + hh;
            float areab = (qx1 - qx0) * (qy1 - qy0);
            unsigned pk = 0u;
            for (int tt = 0; tt < NT_; tt++) {
                float4 tb = trb[tt];
                float iou = iou_fast(tb.x, tb.y, tb.z, tb.w, tra[tt],
                                     qx0, qy0, qx1, qy1, areab);
                unsigned cand = ((__float_as_uint(iou) & 0xFFFFFFFCu) << 2)
                              | (unsigned)(15 - tt);
                pk = (cand > pk) ? cand : pk;
            }
            bool pos0 = (pk >= 0xFC000000u);   // identical rule to main pass
            int t0 = 15 - (int)(pk & 15u);
            size_t bp = (size_t)b * NP_ + p;
            float2 cxyf = ((const float2*)conf)[bp];
            float dd = cxyf.y - cxyf.x;
            float4 ld = ((const float4*)loc)[bp];

            auto sl1_of = [&](int tt) -> float {
                float4 tb = trb[tt];
                float gcx = ((tb.x + tb.z) * 0.5f - prv.x) / (0.1f * prv.z);
                float gcy = ((tb.y + tb.w) * 0.5f - prv.y) / (0.1f * prv.w);
                float gw = __logf((tb.z - tb.x) / prv.z) * 5.0f;
                float gh = __logf((tb.w - tb.y) / prv.w) * 5.0f;
                float d0 = fabsf(ld.x - gcx), d1 = fabsf(ld.y - gcy);
                float d2 = fabsf(ld.z - gw),  d3 = fabsf(ld.w - gh);
                float s = (d0 < 1.0f) ? 0.5f * d0 * d0 : d0 - 0.5f;
                s += (d1 < 1.0f) ? 0.5f * d1 * d1 : d1 - 0.5f;
                s += (d2 < 1.0f) ? 0.5f * d2 * d2 : d2 - 0.5f;
                s += (d3 < 1.0f) ? 0.5f * d3 * d3 : d3 - 0.5f;
                return s;
            };
            float dll = sl1_of(tid) - (pos0 ? sl1_of(t0) : 0.0f);
            atomicAdd(&s_dll, dll);            // single wave -> deterministic order
            if (!pos0) {
                float v = softplus_(dd);       // identical expr to binned value
                int bin = min(HB - 1, (int)(v * HSCALE));
                atomicSub(&hc[bin], 1);
                atomicAdd(&hs[bin], -v);
                atomicAdd(&s_dpc, softplus_(-dd));
                atomicAdd(&s_dnp, 1);
            }
        }
    }
    __syncthreads();

    if (tid < 16) {
        unsigned cacc = 0; float sacc = 0.0f;
        for (int j = 0; j < 64; j++) { cacc += (unsigned)hc[tid * 64 + j]; sacc += hs[tid * 64 + j]; }
        ccnt[tid] = cacc; csm[tid] = sacc;
    }
    __syncthreads();

    if (tid == 0) {
        float sll = s_sll + s_dll;
        float spc = s_spc + s_dpc;
        int n = s_sn + s_dnp;
        int K = 3 * n;
        if (K > NP_ - 1) K = NP_ - 1;
        float tk = 0.0f;
        if (K > 0) {
            unsigned need = (unsigned)K, cum = 0;
            float s = 0.0f;
            int cb = 15;
            for (; cb > 0; --cb) {
                if (cum + ccnt[cb] >= need) break;
                cum += ccnt[cb]; s += csm[cb];
            }
            int bin = cb * 64 + 63;
            for (; bin > cb * 64; --bin) {
                if (cum + (unsigned)hc[bin] >= need) break;
                cum += (unsigned)hc[bin]; s += hs[bin];
            }
            unsigned rem = need - cum;
            int cv = hc[bin];
            float avg = (cv > 0) ? __fdividef(hs[bin], (float)cv) : 0.0f;
            tk = s + (float)rem * avg;
        }
        final_l[b] = sll;
        final_c[b] = spc + tk;
        final_n[b] = n;
        __threadfence();                       // release final_*
        unsigned old = atomicAdd(ticket2, 1u);
        if (old == NB_ - 1) s_last = 1;
    }
    __syncthreads();

    if (s_last) {
        __threadfence();  // acquire: see all other batches' final_* stores
        if (tid < 64) {
            float lv = 0.0f, cv = 0.0f;
            int nv = 0;
            if (tid < NB_) { lv = final_l[tid]; cv = final_c[tid]; nv = final_n[tid]; }
            for (int off = 32; off > 0; off >>= 1) {
                lv += __shfl_down(lv, off, 64);
                cv += __shfl_down(cv, off, 64);
                nv += __shfl_down(nv, off, 64);
            }
            if (tid == 0) {
                float fn = (float)nv;
                out[0] = lv / fn;
                out[1] = cv / fn;
            }
        }
    }
}

extern "C" void kernel_launch(void* const* d_in, const int* in_sizes, int n_in,
                              void* d_out, int out_size, void* d_ws, size_t ws_size,
                              hipStream_t stream) {
    const float* loc = (const float*)d_in[0];
    const float* conf = (const float*)d_in[1];
    const float* priors = (const float*)d_in[2];
    const float* targets = (const float*)d_in[3];
    float* out = (float*)d_out;

    char* w = (char*)d_ws;
    unsigned short* gcnt = (unsigned short*)w;             // 32*64*1024*2 = 4 MB
    float* gsum = (float*)(w + (4u << 20));                // 32*64*1024*4 = 8 MB
    char* acc = w + (12u << 20);
    unsigned long long* bestPart = (unsigned long long*)acc;        // 32*16*64*8 = 256 KB
    float* part_ll = (float*)(acc + 262144);                        // 8 KB
    float* part_pc = (float*)(acc + 262144 + 8192);                 // 8 KB
    int* part_np   = (int*)(acc + 262144 + 16384);                  // 8 KB
    float* final_l = (float*)(acc + 262144 + 24576);                // 128 B
    float* final_c = (float*)(acc + 262144 + 24704);
    int* final_n   = (int*)(acc + 262144 + 24832);
    unsigned* ticketB = (unsigned*)(acc + 262144 + 24960);          // 128 B (32 u32)
    unsigned* ticket2 = (unsigned*)(acc + 262144 + 25088);          // 4 B

    // zero the tickets (256 B region) each launch — stream-ordered, capturable
    hipMemsetAsync((void*)ticketB, 0, 256, stream);

    mainK<<<dim3(NBX, NB_), 256, 0, stream>>>(loc, conf, priors, targets,
                                              gcnt, gsum, bestPart,
                                              part_ll, part_pc, part_np,
                                              final_l, final_c, final_n,
                                              ticketB, ticket2, out);
}

// Round 4
// 167.992 us; speedup vs baseline: 2.2926x; 2.2926x over previous
//
#include <hip/hip_runtime.h>

#define NB_ 32
#define NP_ 65536
#define NT_ 16
#define HB 1024
#define HSCALE 128.0f
#define NBX 64     // kernel1 blocks per batch (1024 priors each)

__device__ __forceinline__ float softplus_(float x) {
    // log(1 + e^x), stable
    return fmaxf(x, 0.0f) + __logf(1.0f + __expf(-fabsf(x)));
}

__device__ __forceinline__ float iou_fast(float tx0, float ty0, float tx1, float ty1, float ta,
                                          float bx0, float by0, float bx1, float by1, float ar) {
    float lx = fmaxf(tx0, bx0), ly = fmaxf(ty0, by0);
    float rx = fminf(tx1, bx1), ry = fminf(ty1, by1);
    float w = fmaxf(rx - lx, 0.0f), h = fmaxf(ry - ly, 0.0f);
    float inter = w * h;
    return __fdividef(inter, ta + ar - inter);
}

// ---- DPP wave64 reductions (result valid in lane 63) ----
#define DPP_STEP(x, t, ctrl, rmask, bmask, OP)                                          \
    t = __builtin_amdgcn_update_dpp(0, (x), (ctrl), (rmask), (bmask), true); OP;

__device__ __forceinline__ unsigned wave_max_u32(unsigned v) {
    int x = (int)v, t;
    DPP_STEP(x, t, 0x111, 0xf, 0xf, x = ((unsigned)t > (unsigned)x) ? t : x)
    DPP_STEP(x, t, 0x112, 0xf, 0xf, x = ((unsigned)t > (unsigned)x) ? t : x)
    DPP_STEP(x, t, 0x114, 0xf, 0xe, x = ((unsigned)t > (unsigned)x) ? t : x)
    DPP_STEP(x, t, 0x118, 0xf, 0xc, x = ((unsigned)t > (unsigned)x) ? t : x)
    DPP_STEP(x, t, 0x142, 0xa, 0xf, x = ((unsigned)t > (unsigned)x) ? t : x)
    DPP_STEP(x, t, 0x143, 0xc, 0xf, x = ((unsigned)t > (unsigned)x) ? t : x)
    return (unsigned)x;
}

__device__ __forceinline__ float wave_sum_f32(float v) {
    int x = __float_as_int(v), t;
    float f;
    DPP_STEP(x, t, 0x111, 0xf, 0xf, f = __int_as_float(x) + __int_as_float(t); x = __float_as_int(f))
    DPP_STEP(x, t, 0x112, 0xf, 0xf, f = __int_as_float(x) + __int_as_float(t); x = __float_as_int(f))
    DPP_STEP(x, t, 0x114, 0xf, 0xe, f = __int_as_float(x) + __int_as_float(t); x = __float_as_int(f))
    DPP_STEP(x, t, 0x118, 0xf, 0xc, f = __int_as_float(x) + __int_as_float(t); x = __float_as_int(f))
    DPP_STEP(x, t, 0x142, 0xa, 0xf, f = __int_as_float(x) + __int_as_float(t); x = __float_as_int(f))
    DPP_STEP(x, t, 0x143, 0xc, 0xf, f = __int_as_float(x) + __int_as_float(t); x = __float_as_int(f))
    return __int_as_float(x);
}

__device__ __forceinline__ int wave_sum_i32(int v) {
    int x = v, t;
    DPP_STEP(x, t, 0x111, 0xf, 0xf, x = x + t)
    DPP_STEP(x, t, 0x112, 0xf, 0xf, x = x + t)
    DPP_STEP(x, t, 0x114, 0xf, 0xe, x = x + t)
    DPP_STEP(x, t, 0x118, 0xf, 0xc, x = x + t)
    DPP_STEP(x, t, 0x142, 0xa, 0xf, x = x + t)
    DPP_STEP(x, t, 0x143, 0xc, 0xf, x = x + t)
    return x;
}

// Kernel 1: fused match + losses + per-block histogram (R2-proven form).
// R10 note: single-kernel fusion (R3) regressed 6x — per-block device-scope
// release fences (2048x buffer_wbl2) thrash every XCD L2. Two-kernel structure
// gets the flush once at the kernel boundary. Do not re-fuse.
__global__ void __launch_bounds__(256) mainK(
    const float* __restrict__ loc, const float* __restrict__ conf,
    const float* __restrict__ priors, const float* __restrict__ targets,
    unsigned short* __restrict__ gcnt, float* __restrict__ gsum,
    unsigned long long* __restrict__ bestPart,
    float* __restrict__ part_ll, float* __restrict__ part_pc, int* __restrict__ part_np,
    unsigned* __restrict__ ticketB)
{
    const int bx = blockIdx.x, b = blockIdx.y, tid = threadIdx.x;

    __shared__ float4 trb[NT_];   // x0,y0,x1,y1
    __shared__ float tra[NT_];    // area
    __shared__ int hc[HB];
    __shared__ float hs[HB];
    __shared__ unsigned wkey[4][NT_], wp[4][NT_];
    __shared__ float sh_ll[4], sh_pc[4];
    __shared__ int sh_np[4];

    // init tickets for kernel2 (consumed only after full drain — race-free)
    if (b == 0 && bx == 0 && tid < 33) ticketB[tid] = 0u;

    for (int i = tid; i < HB; i += 256) { hc[i] = 0; hs[i] = 0.0f; }
    if (tid < NT_) {
        const float* tp = targets + ((size_t)b * NT_ + tid) * 5;
        float x0 = tp[0], y0 = tp[1], x1 = tp[2], y1 = tp[3];
        trb[tid] = make_float4(x0, y0, x1, y1);
        tra[tid] = (x1 - x0) * (y1 - y0);
    }
    __syncthreads();

    const int pbase = bx * 1024 + tid;
    float pbx0[4], pby0[4], pbx1[4], pby1[4], par[4];
    float2 cxy[4];
#pragma unroll
    for (int i = 0; i < 4; i++) {
        float4 pr = ((const float4*)priors)[pbase + 256 * i];
        cxy[i] = ((const float2*)conf)[(size_t)b * NP_ + pbase + 256 * i];  // in flight during t-loop
        float hw = pr.z * 0.5f, hh = pr.w * 0.5f;
        pbx0[i] = pr.x - hw; pby0[i] = pr.y - hh;
        pbx1[i] = pr.x + hw; pby1[i] = pr.y + hh;
        par[i] = (pbx1[i] - pbx0[i]) * (pby1[i] - pby0[i]);
    }

    unsigned pkey[4] = {0u, 0u, 0u, 0u};  // per-prior best (iou_key | (15-t))
    unsigned tkey[NT_];                   // per-truth best (iou_key | (15-i))
#pragma unroll
    for (int t = 0; t < NT_; t++) tkey[t] = 0u;

#pragma unroll
    for (int t = 0; t < NT_; t++) {
        float4 tb = trb[t];          // ds_read_b128 (broadcast)
        float ta = tra[t];           // ds_read_b32
#pragma unroll
        for (int i = 0; i < 4; i++) {
            float iou = iou_fast(tb.x, tb.y, tb.z, tb.w, ta,
                                 pbx0[i], pby0[i], pbx1[i], pby1[i], par[i]);
            // monotone u32 key; 2 LSB mantissa bits -> 4-bit tie-break index
            // (ties prefer smaller t / smaller prior index)
            unsigned base = (__float_as_uint(iou) & 0xFFFFFFFCu) << 2;
            unsigned kt = base | (unsigned)(15 - t);
            unsigned kp = base | (unsigned)(15 - i);
            pkey[i] = (kt > pkey[i]) ? kt : pkey[i];
            tkey[t] = (kp > tkey[t]) ? kp : tkey[t];
        }
    }

    float ll_acc = 0.0f, pc_acc = 0.0f;
    int np_acc = 0;
#pragma unroll
    for (int i = 0; i < 4; i++) {
        int p = pbase + 256 * i;
        size_t bp = (size_t)b * NP_ + p;
        bool pos = (pkey[i] >= 0xFC000000u);  // iou >= 0.5 (0.5 has zero low bits)
        float dd = cxy[i].y - cxy[i].x;
        float v = pos ? 0.0f : softplus_(dd);  // loss_c_mine
        int bin = min(HB - 1, (int)(v * HSCALE));
        atomicAdd(&hc[bin], 1);
        atomicAdd(&hs[bin], v);
        if (pos) {
            np_acc++;
            pc_acc += softplus_(-dd);  // lse - c.y
            int t = 15 - (int)(pkey[i] & 15u);
            float4 tb = trb[t];
            float4 prv = ((const float4*)priors)[p];  // reload: same bits as staging load
            float gcx = ((tb.x + tb.z) * 0.5f - prv.x) / (0.1f * prv.z);
            float gcy = ((tb.y + tb.w) * 0.5f - prv.y) / (0.1f * prv.w);
            float gw = __logf((tb.z - tb.x) / prv.z) * 5.0f;
            float gh = __logf((tb.w - tb.y) / prv.w) * 5.0f;
            float4 ld = ((const float4*)loc)[bp];
            float d0 = fabsf(ld.x - gcx), d1 = fabsf(ld.y - gcy);
            float d2 = fabsf(ld.z - gw),  d3 = fabsf(ld.w - gh);
            ll_acc += (d0 < 1.0f) ? 0.5f * d0 * d0 : d0 - 0.5f;
            ll_acc += (d1 < 1.0f) ? 0.5f * d1 * d1 : d1 - 0.5f;
            ll_acc += (d2 < 1.0f) ? 0.5f * d2 * d2 : d2 - 0.5f;
            ll_acc += (d3 < 1.0f) ? 0.5f * d3 * d3 : d3 - 0.5f;
        }
    }

    // per-wave reductions — DPP chains (VALU), no LDS pipe
    const int wave = tid >> 6, lane = tid & 63;
#pragma unroll
    for (int t = 0; t < NT_; t++) {
        unsigned k = tkey[t];
        unsigned m = (unsigned)__builtin_amdgcn_readlane((int)wave_max_u32(k), 63);
        unsigned long long ball = __ballot(k == m);
        if (lane == 0) {
            int l = __ffsll((long long)ball) - 1;  // lowest lane = smallest p (same i)
            int ci = 15 - (int)(m & 15u);
            int p = bx * 1024 + ci * 256 + wave * 64 + l;
            wkey[wave][t] = m;
            wp[wave][t] = (unsigned)p;
        }
    }
    {
        float llw = wave_sum_f32(ll_acc);
        float pcw = wave_sum_f32(pc_acc);
        int npw = wave_sum_i32(np_acc);
        if (lane == 63) { sh_ll[wave] = llw; sh_pc[wave] = pcw; sh_np[wave] = npw; }
    }
    __syncthreads();

    if (tid < NT_) {
        unsigned bk = wkey[0][tid], bpv = wp[0][tid];
        for (int w = 1; w < 4; w++) {
            unsigned k2 = wkey[w][tid], p2 = wp[w][tid];
            if (k2 > bk || (k2 == bk && p2 < bpv)) { bk = k2; bpv = p2; }
        }
        unsigned long long pk = (((unsigned long long)bk) << 32) | (unsigned)(~bpv);
        bestPart[((size_t)b * NT_ + tid) * NBX + bx] = pk;   // plain store
    }
    if (tid == 0) {
        part_ll[b * NBX + bx] = sh_ll[0] + sh_ll[1] + sh_ll[2] + sh_ll[3];
        part_pc[b * NBX + bx] = sh_pc[0] + sh_pc[1] + sh_pc[2] + sh_pc[3];
        part_np[b * NBX + bx] = sh_np[0] + sh_np[1] + sh_np[2] + sh_np[3];
    }
    // deterministic per-block hist writeback (coalesced); counts fit u16 (<=1024)
    unsigned short* gc = gcnt + ((size_t)(b * NBX + bx)) * HB;
    float* gs = gsum + ((size_t)(b * NBX + bx)) * HB;
    for (int i = tid; i < HB; i += 256) { gc[i] = (unsigned short)hc[i]; gs[i] = hs[i]; }
}

// Kernel 2 (R10): 2 blocks per batch. Each block merges a 512-bin half of the
// hist over all 64 per-block hists (j-range split 2-way per thread, combined
// in FIXED order sA+sB -> deterministic). The pair joins via per-batch ticket
// (64 release fences total — the cheap regime). The elected combiner does the
// bestPart wave-merge, DPP part sums, fixup, selection; last combiner reduces
// across batches (ticket2).
__global__ void __launch_bounds__(1024) finishK(
    const float* __restrict__ loc, const float* __restrict__ conf,
    const float* __restrict__ priors, const float* __restrict__ targets,
    const unsigned short* __restrict__ gcnt, const float* __restrict__ gsum,
    const unsigned long long* __restrict__ bestPart,
    const float* __restrict__ part_ll, const float* __restrict__ part_pc,
    const int* __restrict__ part_np,
    int* __restrict__ hcM, float* __restrict__ hsM,
    float* __restrict__ final_l, float* __restrict__ final_c, int* __restrict__ final_n,
    unsigned* __restrict__ ticketB, unsigned* __restrict__ ticket2,
    float* __restrict__ out)
{
    const int z = blockIdx.x, b = blockIdx.y, tid = threadIdx.x;  // 1024 threads
    __shared__ int hc[HB];
    __shared__ float hs[HB];
    __shared__ float4 trb[NT_];
    __shared__ float tra[NT_];
    __shared__ unsigned ps[NT_];
    __shared__ float s_dll, s_dpc, s_sll, s_spc;
    __shared__ int s_dnp, s_sn, s_last;
    __shared__ unsigned ccnt[16];
    __shared__ float csm[16];
    __shared__ unsigned s_old;

    if (tid < NT_) {
        const float* tp = targets + ((size_t)b * NT_ + tid) * 5;
        float x0 = tp[0], y0 = tp[1], x1 = tp[2], y1 = tp[3];
        trb[tid] = make_float4(x0, y0, x1, y1);
        tra[tid] = (x1 - x0) * (y1 - y0);
    }

    // ---- phase A: merge this block's 512-bin half over 64 hists ----
    {
        const int binl = tid & 511;        // 0..511
        const int half = tid >> 9;         // 0 or 1 (j-range split)
        const int bin  = z * 512 + binl;
        const size_t base = (size_t)(b * NBX) * HB + bin;
        const int j0 = half * 32;
        int c = 0; float s = 0.0f;
#pragma unroll 8
        for (int j = 0; j < 32; j++) {
            size_t o = base + (size_t)(j0 + j) * HB;
            c += (int)gcnt[o];
            s += gsum[o];
        }
        hc[half * 512 + binl] = c;
        hs[half * 512 + binl] = s;
    }
    __syncthreads();
    if (tid < 512) {
        // FIXED combine order (half0 + half1): deterministic
        int   mc = hc[tid] + hc[512 + tid];
        float ms = hs[tid] + hs[512 + tid];
        hcM[(size_t)b * HB + z * 512 + tid] = mc;
        hsM[(size_t)b * HB + z * 512 + tid] = ms;
    }
    __syncthreads();           // all stores executed (barrier drains vmcnt)
    __threadfence();           // release our half to the other XCD
    if (tid == 0) s_old = atomicAdd(&ticketB[b], 1u);
    __syncthreads();
    if (s_old != 1u) return;   // first-arriving block of the pair exits
    __threadfence();           // acquire the other half

    // ---- phase B (combiner): load merged hist, merge bests, fixup, select ----
    hc[tid] = hcM[(size_t)b * HB + tid];
    hs[tid] = hsM[(size_t)b * HB + tid];
    if (tid == 0) { s_dll = 0.0f; s_dpc = 0.0f; s_dnp = 0; s_last = 0; }

    // bestPart: one wave per truth, 64 lanes = 64 partials; u64 max is
    // order-free and keys are unique (low bits = ~p) -> deterministic
    {
        const int tr_i = tid >> 6, lane = tid & 63;
        unsigned long long v = bestPart[((size_t)b * NT_ + tr_i) * NBX + lane];
        for (int off = 32; off > 0; off >>= 1) {
            unsigned long long u = __shfl_down(v, off, 64);
            v = (u > v) ? u : v;
        }
        if (lane == 0) ps[tr_i] = ~((unsigned)(v & 0xffffffffULL));
    }
    // part sums: 64 lanes, fixed DPP tree (deterministic)
    if (tid < 64) {
        float lv = part_ll[b * NBX + tid];
        float pv = part_pc[b * NBX + tid];
        int nv = part_np[b * NBX + tid];
        lv = wave_sum_f32(lv); pv = wave_sum_f32(pv); nv = wave_sum_i32(nv);
        if (tid == 63) { s_sll = lv; s_spc = pv; s_sn = nv; }
    }
    __syncthreads();

    // fixup (16 threads) — adjustments into LDS; identical math to main pass
    if (tid < NT_) {
        unsigned p = ps[tid];
        bool active = true;
        for (int u = tid + 1; u < NT_; u++)
            if (ps[u] == p) { active = false; break; }  // last-wins dedup
        if (active) {
            float4 prv = ((const float4*)priors)[p];
            float hw = prv.z * 0.5f, hh = prv.w * 0.5f;
            float qx0 = prv.x - hw, qy0 = prv.y - hh;
            float qx1 = prv.x + hw, qy1 = prv.y + hh;
            float areab = (qx1 - qx0) * (qy1 - qy0);
            unsigned pk = 0u;
            for (int tt = 0; tt < NT_; tt++) {
                float4 tb = trb[tt];
                float iou = iou_fast(tb.x, tb.y, tb.z, tb.w, tra[tt],
                                     qx0, qy0, qx1, qy1, areab);
                unsigned cand = ((__float_as_uint(iou) & 0xFFFFFFFCu) << 2)
                              | (unsigned)(15 - tt);
                pk = (cand > pk) ? cand : pk;
            }
            bool pos0 = (pk >= 0xFC000000u);   // identical rule to kernel1
            int t0 = 15 - (int)(pk & 15u);
            size_t bp = (size_t)b * NP_ + p;
            float2 cxyf = ((const float2*)conf)[bp];
            float dd = cxyf.y - cxyf.x;
            float4 ld = ((const float4*)loc)[bp];

            auto sl1_of = [&](int tt) -> float {
                float4 tb = trb[tt];
                float gcx = ((tb.x + tb.z) * 0.5f - prv.x) / (0.1f * prv.z);
                float gcy = ((tb.y + tb.w) * 0.5f - prv.y) / (0.1f * prv.w);
                float gw = __logf((tb.z - tb.x) / prv.z) * 5.0f;
                float gh = __logf((tb.w - tb.y) / prv.w) * 5.0f;
                float d0 = fabsf(ld.x - gcx), d1 = fabsf(ld.y - gcy);
                float d2 = fabsf(ld.z - gw),  d3 = fabsf(ld.w - gh);
                float s = (d0 < 1.0f) ? 0.5f * d0 * d0 : d0 - 0.5f;
                s += (d1 < 1.0f) ? 0.5f * d1 * d1 : d1 - 0.5f;
                s += (d2 < 1.0f) ? 0.5f * d2 * d2 : d2 - 0.5f;
                s += (d3 < 1.0f) ? 0.5f * d3 * d3 : d3 - 0.5f;
                return s;
            };
            float dll = sl1_of(tid) - (pos0 ? sl1_of(t0) : 0.0f);
            atomicAdd(&s_dll, dll);            // single wave -> fixed HW order
            if (!pos0) {
                float v = softplus_(dd);       // identical expr to binned value
                int bin = min(HB - 1, (int)(v * HSCALE));
                atomicSub(&hc[bin], 1);
                atomicAdd(&hs[bin], -v);
                atomicAdd(&s_dpc, softplus_(-dd));
                atomicAdd(&s_dnp, 1);
            }
        }
    }
    __syncthreads();

    if (tid < 16) {
        unsigned cacc = 0; float sacc = 0.0f;
        for (int j = 0; j < 64; j++) { cacc += (unsigned)hc[tid * 64 + j]; sacc += hs[tid * 64 + j]; }
        ccnt[tid] = cacc; csm[tid] = sacc;
    }
    __syncthreads();

    if (tid == 0) {
        float sll = s_sll + s_dll;
        float spc = s_spc + s_dpc;
        int n = s_sn + s_dnp;
        int K = 3 * n;
        if (K > NP_ - 1) K = NP_ - 1;
        float tk = 0.0f;
        if (K > 0) {
            unsigned need = (unsigned)K, cum = 0;
            float s = 0.0f;
            int cb = 15;
            for (; cb > 0; --cb) {
                if (cum + ccnt[cb] >= need) break;
                cum += ccnt[cb]; s += csm[cb];
            }
            int bin = cb * 64 + 63;
            for (; bin > cb * 64; --bin) {
                if (cum + (unsigned)hc[bin] >= need) break;
                cum += (unsigned)hc[bin]; s += hs[bin];
            }
            unsigned rem = need - cum;
            int cv = hc[bin];
            float avg = (cv > 0) ? __fdividef(hs[bin], (float)cv) : 0.0f;
            tk = s + (float)rem * avg;
        }
        final_l[b] = sll;
        final_c[b] = spc + tk;
        final_n[b] = n;
        __threadfence();                       // release final_*
        unsigned old = atomicAdd(ticket2, 1u);
        if (old == NB_ - 1) s_last = 1;
    }
    __syncthreads();

    if (s_last) {
        __threadfence();  // acquire: see all other batches' final_* stores
        if (tid < 64) {
            float lv = 0.0f, cv = 0.0f;
            int nv = 0;
            if (tid < NB_) { lv = final_l[tid]; cv = final_c[tid]; nv = final_n[tid]; }
            for (int off = 32; off > 0; off >>= 1) {
                lv += __shfl_down(lv, off, 64);
                cv += __shfl_down(cv, off, 64);
                nv += __shfl_down(nv, off, 64);
            }
            if (tid == 0) {
                float fn = (float)nv;
                out[0] = lv / fn;
                out[1] = cv / fn;
            }
        }
    }
}

extern "C" void kernel_launch(void* const* d_in, const int* in_sizes, int n_in,
                              void* d_out, int out_size, void* d_ws, size_t ws_size,
                              hipStream_t stream) {
    const float* loc = (const float*)d_in[0];
    const float* conf = (const float*)d_in[1];
    const float* priors = (const float*)d_in[2];
    const float* targets = (const float*)d_in[3];
    float* out = (float*)d_out;

    char* w = (char*)d_ws;
    unsigned short* gcnt = (unsigned short*)w;             // 32*64*1024*2 = 4 MB
    float* gsum = (float*)(w + (4u << 20));                // 32*64*1024*4 = 8 MB
    char* acc = w + (12u << 20);
    unsigned long long* bestPart = (unsigned long long*)acc;        // 256 KB
    float* part_ll = (float*)(acc + 262144);                        // 8 KB
    float* part_pc = (float*)(acc + 270336);                        // 8 KB
    int* part_np   = (int*)(acc + 278528);                          // 8 KB
    float* final_l = (float*)(acc + 286720);                        // 128 B
    float* final_c = (float*)(acc + 286848);                        // 128 B
    int* final_n   = (int*)(acc + 286976);                          // 128 B
    unsigned* ticketB = (unsigned*)(acc + 287104);                  // 33 u32 (B tickets + ticket2)
    unsigned* ticket2 = ticketB + 32;
    int* hcM   = (int*)(acc + 287360);                              // 32*1024*4 = 128 KB
    float* hsM = (float*)(acc + 287360 + 131072);                   // 128 KB

    mainK<<<dim3(NBX, NB_), 256, 0, stream>>>(loc, conf, priors, targets,
                                              gcnt, gsum, bestPart,
                                              part_ll, part_pc, part_np, ticketB);
    finishK<<<dim3(2, NB_), 1024, 0, stream>>>(loc, conf, priors, targets,
                                               gcnt, gsum, bestPart,
                                               part_ll, part_pc, part_np,
                                               hcM, hsM,
                                               final_l, final_c, final_n,
                                               ticketB, ticket2, out);
}

// Round 5
// 138.166 us; speedup vs baseline: 2.7875x; 1.2159x over previous
//
#include <hip/hip_runtime.h>

#define NB_ 32
#define NP_ 65536
#define NT_ 16
#define HB 1024
#define HSCALE 128.0f
#define NBX 64     // kernel1 blocks per batch (1024 priors each)

__device__ __forceinline__ float softplus_(float x) {
    // log(1 + e^x), stable
    return fmaxf(x, 0.0f) + __logf(1.0f + __expf(-fabsf(x)));
}

__device__ __forceinline__ float iou_fast(float tx0, float ty0, float tx1, float ty1, float ta,
                                          float bx0, float by0, float bx1, float by1, float ar) {
    float lx = fmaxf(tx0, bx0), ly = fmaxf(ty0, by0);
    float rx = fminf(tx1, bx1), ry = fminf(ty1, by1);
    float w = fmaxf(rx - lx, 0.0f), h = fmaxf(ry - ly, 0.0f);
    float inter = w * h;
    return __fdividef(inter, ta + ar - inter);
}

// ---- DPP wave64 reductions (result valid in lane 63) ----
#define DPP_STEP(x, t, ctrl, rmask, bmask, OP)                                          \
    t = __builtin_amdgcn_update_dpp(0, (x), (ctrl), (rmask), (bmask), true); OP;

__device__ __forceinline__ unsigned wave_max_u32(unsigned v) {
    int x = (int)v, t;
    DPP_STEP(x, t, 0x111, 0xf, 0xf, x = ((unsigned)t > (unsigned)x) ? t : x)
    DPP_STEP(x, t, 0x112, 0xf, 0xf, x = ((unsigned)t > (unsigned)x) ? t : x)
    DPP_STEP(x, t, 0x114, 0xf, 0xe, x = ((unsigned)t > (unsigned)x) ? t : x)
    DPP_STEP(x, t, 0x118, 0xf, 0xc, x = ((unsigned)t > (unsigned)x) ? t : x)
    DPP_STEP(x, t, 0x142, 0xa, 0xf, x = ((unsigned)t > (unsigned)x) ? t : x)
    DPP_STEP(x, t, 0x143, 0xc, 0xf, x = ((unsigned)t > (unsigned)x) ? t : x)
    return (unsigned)x;
}

__device__ __forceinline__ float wave_sum_f32(float v) {
    int x = __float_as_int(v), t;
    float f;
    DPP_STEP(x, t, 0x111, 0xf, 0xf, f = __int_as_float(x) + __int_as_float(t); x = __float_as_int(f))
    DPP_STEP(x, t, 0x112, 0xf, 0xf, f = __int_as_float(x) + __int_as_float(t); x = __float_as_int(f))
    DPP_STEP(x, t, 0x114, 0xf, 0xe, f = __int_as_float(x) + __int_as_float(t); x = __float_as_int(f))
    DPP_STEP(x, t, 0x118, 0xf, 0xc, f = __int_as_float(x) + __int_as_float(t); x = __float_as_int(f))
    DPP_STEP(x, t, 0x142, 0xa, 0xf, f = __int_as_float(x) + __int_as_float(t); x = __float_as_int(f))
    DPP_STEP(x, t, 0x143, 0xc, 0xf, f = __int_as_float(x) + __int_as_float(t); x = __float_as_int(f))
    return __int_as_float(x);
}

__device__ __forceinline__ int wave_sum_i32(int v) {
    int x = v, t;
    DPP_STEP(x, t, 0x111, 0xf, 0xf, x = x + t)
    DPP_STEP(x, t, 0x112, 0xf, 0xf, x = x + t)
    DPP_STEP(x, t, 0x114, 0xf, 0xe, x = x + t)
    DPP_STEP(x, t, 0x118, 0xf, 0xc, x = x + t)
    DPP_STEP(x, t, 0x142, 0xa, 0xf, x = x + t)
    DPP_STEP(x, t, 0x143, 0xc, 0xf, x = x + t)
    return x;
}

// Kernel 1: fused match + losses + per-block histogram (R2-proven form).
// R10/R11 notes: intra-kernel cross-XCD joins regress — R3 (2048 fences, 6x),
// R4 (96 fences + hist round-trip, finishK 49us @ 0.7% VALU). Keep kernels
// fence-free; use kernel boundaries for ordering. Do not re-fuse.
__global__ void __launch_bounds__(256) mainK(
    const float* __restrict__ loc, const float* __restrict__ conf,
    const float* __restrict__ priors, const float* __restrict__ targets,
    unsigned short* __restrict__ gcnt, float* __restrict__ gsum,
    unsigned long long* __restrict__ bestPart,
    float* __restrict__ part_ll, float* __restrict__ part_pc, int* __restrict__ part_np)
{
    const int bx = blockIdx.x, b = blockIdx.y, tid = threadIdx.x;

    __shared__ float4 trb[NT_];   // x0,y0,x1,y1
    __shared__ float tra[NT_];    // area
    __shared__ int hc[HB];
    __shared__ float hs[HB];
    __shared__ unsigned wkey[4][NT_], wp[4][NT_];
    __shared__ float sh_ll[4], sh_pc[4];
    __shared__ int sh_np[4];

    for (int i = tid; i < HB; i += 256) { hc[i] = 0; hs[i] = 0.0f; }
    if (tid < NT_) {
        const float* tp = targets + ((size_t)b * NT_ + tid) * 5;
        float x0 = tp[0], y0 = tp[1], x1 = tp[2], y1 = tp[3];
        trb[tid] = make_float4(x0, y0, x1, y1);
        tra[tid] = (x1 - x0) * (y1 - y0);
    }
    __syncthreads();

    const int pbase = bx * 1024 + tid;
    float pbx0[4], pby0[4], pbx1[4], pby1[4], par[4];
    float2 cxy[4];
#pragma unroll
    for (int i = 0; i < 4; i++) {
        float4 pr = ((const float4*)priors)[pbase + 256 * i];
        cxy[i] = ((const float2*)conf)[(size_t)b * NP_ + pbase + 256 * i];  // in flight during t-loop
        float hw = pr.z * 0.5f, hh = pr.w * 0.5f;
        pbx0[i] = pr.x - hw; pby0[i] = pr.y - hh;
        pbx1[i] = pr.x + hw; pby1[i] = pr.y + hh;
        par[i] = (pbx1[i] - pbx0[i]) * (pby1[i] - pby0[i]);
    }

    unsigned pkey[4] = {0u, 0u, 0u, 0u};  // per-prior best (iou_key | (15-t))
    unsigned tkey[NT_];                   // per-truth best (iou_key | (15-i))
#pragma unroll
    for (int t = 0; t < NT_; t++) tkey[t] = 0u;

#pragma unroll
    for (int t = 0; t < NT_; t++) {
        float4 tb = trb[t];          // ds_read_b128 (broadcast)
        float ta = tra[t];           // ds_read_b32
#pragma unroll
        for (int i = 0; i < 4; i++) {
            float iou = iou_fast(tb.x, tb.y, tb.z, tb.w, ta,
                                 pbx0[i], pby0[i], pbx1[i], pby1[i], par[i]);
            // monotone u32 key; 2 LSB mantissa bits -> 4-bit tie-break index
            // (ties prefer smaller t / smaller prior index)
            unsigned base = (__float_as_uint(iou) & 0xFFFFFFFCu) << 2;
            unsigned kt = base | (unsigned)(15 - t);
            unsigned kp = base | (unsigned)(15 - i);
            pkey[i] = (kt > pkey[i]) ? kt : pkey[i];
            tkey[t] = (kp > tkey[t]) ? kp : tkey[t];
        }
    }

    float ll_acc = 0.0f, pc_acc = 0.0f;
    int np_acc = 0;
#pragma unroll
    for (int i = 0; i < 4; i++) {
        int p = pbase + 256 * i;
        size_t bp = (size_t)b * NP_ + p;
        bool pos = (pkey[i] >= 0xFC000000u);  // iou >= 0.5 (0.5 has zero low bits)
        float dd = cxy[i].y - cxy[i].x;
        float v = pos ? 0.0f : softplus_(dd);  // loss_c_mine
        int bin = min(HB - 1, (int)(v * HSCALE));
        atomicAdd(&hc[bin], 1);
        atomicAdd(&hs[bin], v);
        if (pos) {
            np_acc++;
            pc_acc += softplus_(-dd);  // lse - c.y
            int t = 15 - (int)(pkey[i] & 15u);
            float4 tb = trb[t];
            float4 prv = ((const float4*)priors)[p];  // reload: same bits as staging load
            float gcx = ((tb.x + tb.z) * 0.5f - prv.x) / (0.1f * prv.z);
            float gcy = ((tb.y + tb.w) * 0.5f - prv.y) / (0.1f * prv.w);
            float gw = __logf((tb.z - tb.x) / prv.z) * 5.0f;
            float gh = __logf((tb.w - tb.y) / prv.w) * 5.0f;
            float4 ld = ((const float4*)loc)[bp];
            float d0 = fabsf(ld.x - gcx), d1 = fabsf(ld.y - gcy);
            float d2 = fabsf(ld.z - gw),  d3 = fabsf(ld.w - gh);
            ll_acc += (d0 < 1.0f) ? 0.5f * d0 * d0 : d0 - 0.5f;
            ll_acc += (d1 < 1.0f) ? 0.5f * d1 * d1 : d1 - 0.5f;
            ll_acc += (d2 < 1.0f) ? 0.5f * d2 * d2 : d2 - 0.5f;
            ll_acc += (d3 < 1.0f) ? 0.5f * d3 * d3 : d3 - 0.5f;
        }
    }

    // per-wave reductions — DPP chains (VALU), no LDS pipe
    const int wave = tid >> 6, lane = tid & 63;
#pragma unroll
    for (int t = 0; t < NT_; t++) {
        unsigned k = tkey[t];
        unsigned m = (unsigned)__builtin_amdgcn_readlane((int)wave_max_u32(k), 63);
        unsigned long long ball = __ballot(k == m);
        if (lane == 0) {
            int l = __ffsll((long long)ball) - 1;  // lowest lane = smallest p (same i)
            int ci = 15 - (int)(m & 15u);
            int p = bx * 1024 + ci * 256 + wave * 64 + l;
            wkey[wave][t] = m;
            wp[wave][t] = (unsigned)p;
        }
    }
    {
        float llw = wave_sum_f32(ll_acc);
        float pcw = wave_sum_f32(pc_acc);
        int npw = wave_sum_i32(np_acc);
        if (lane == 63) { sh_ll[wave] = llw; sh_pc[wave] = pcw; sh_np[wave] = npw; }
    }
    __syncthreads();

    if (tid < NT_) {
        unsigned bk = wkey[0][tid], bpv = wp[0][tid];
        for (int w = 1; w < 4; w++) {
            unsigned k2 = wkey[w][tid], p2 = wp[w][tid];
            if (k2 > bk || (k2 == bk && p2 < bpv)) { bk = k2; bpv = p2; }
        }
        unsigned long long pk = (((unsigned long long)bk) << 32) | (unsigned)(~bpv);
        bestPart[((size_t)b * NT_ + tid) * NBX + bx] = pk;   // plain store
    }
    if (tid == 0) {
        part_ll[b * NBX + bx] = sh_ll[0] + sh_ll[1] + sh_ll[2] + sh_ll[3];
        part_pc[b * NBX + bx] = sh_pc[0] + sh_pc[1] + sh_pc[2] + sh_pc[3];
        part_np[b * NBX + bx] = sh_np[0] + sh_np[1] + sh_np[2] + sh_np[3];
    }
    // deterministic per-block hist writeback (coalesced); counts fit u16 (<=1024)
    unsigned short* gc = gcnt + ((size_t)(b * NBX + bx)) * HB;
    float* gs = gsum + ((size_t)(b * NBX + bx)) * HB;
    for (int i = tid; i < HB; i += 256) { gc[i] = (unsigned short)hc[i]; gs[i] = hs[i]; }
}

// Kernel 2 (R11): one block per batch, FULLY independent — zero fences, zero
// tickets, zero global atomics. Hist merge one bin/thread with j split into
// two fixed-order halves (ILP); bestPart via 16 waves x 64-lane shuffle-max
// (u64 keys unique -> order-free, R4-proven); part sums via DPP fixed tree
// (R4-proven). Writes final_l/c/n; lastK (boundary-ordered) does the division.
__global__ void __launch_bounds__(1024) finishK(
    const float* __restrict__ loc, const float* __restrict__ conf,
    const float* __restrict__ priors, const float* __restrict__ targets,
    const unsigned short* __restrict__ gcnt, const float* __restrict__ gsum,
    const unsigned long long* __restrict__ bestPart,
    const float* __restrict__ part_ll, const float* __restrict__ part_pc,
    const int* __restrict__ part_np,
    float* __restrict__ final_l, float* __restrict__ final_c, int* __restrict__ final_n)
{
    const int b = blockIdx.x, tid = threadIdx.x;  // 1024 threads
    __shared__ int hc[HB];
    __shared__ float hs[HB];
    __shared__ float4 trb[NT_];
    __shared__ float tra[NT_];
    __shared__ unsigned ps[NT_];
    __shared__ float s_dll, s_dpc, s_sll, s_spc;
    __shared__ int s_dnp, s_sn;
    __shared__ unsigned ccnt[16];
    __shared__ float csm[16];

    if (tid == 0) { s_dll = 0.0f; s_dpc = 0.0f; s_dnp = 0; }
    if (tid < NT_) {
        const float* tp = targets + ((size_t)b * NT_ + tid) * 5;
        float x0 = tp[0], y0 = tp[1], x1 = tp[2], y1 = tp[3];
        trb[tid] = make_float4(x0, y0, x1, y1);
        tra[tid] = (x1 - x0) * (y1 - y0);
    }

    // hist merge: one bin per thread; j-range in two fixed-order halves
    {
        const size_t base = (size_t)(b * NBX) * HB + tid;
        int cA = 0, cB = 0; float sA = 0.0f, sB = 0.0f;
#pragma unroll 8
        for (int j = 0; j < 32; j++) {
            size_t oA = base + (size_t)j * HB;
            size_t oB = base + (size_t)(32 + j) * HB;
            cA += (int)gcnt[oA]; sA += gsum[oA];
            cB += (int)gcnt[oB]; sB += gsum[oB];
        }
        hc[tid] = cA + cB;          // fixed combine order -> deterministic
        hs[tid] = sA + sB;
    }

    // bestPart: one wave per truth, 64 lanes = 64 partials; u64 max is
    // order-free and keys are unique (low bits = ~p) -> deterministic
    {
        const int tr_i = tid >> 6, lane = tid & 63;
        unsigned long long v = bestPart[((size_t)b * NT_ + tr_i) * NBX + lane];
        for (int off = 32; off > 0; off >>= 1) {
            unsigned long long u = __shfl_down(v, off, 64);
            v = (u > v) ? u : v;
        }
        if (lane == 0) ps[tr_i] = ~((unsigned)(v & 0xffffffffULL));
    }
    // part sums: 64 lanes, fixed DPP tree (deterministic)
    if (tid < 64) {
        float lv = part_ll[b * NBX + tid];
        float pv = part_pc[b * NBX + tid];
        int nv = part_np[b * NBX + tid];
        lv = wave_sum_f32(lv); pv = wave_sum_f32(pv); nv = wave_sum_i32(nv);
        if (tid == 63) { s_sll = lv; s_spc = pv; s_sn = nv; }
    }
    __syncthreads();

    // fixup (16 threads) — adjustments into LDS; identical math to main pass
    if (tid < NT_) {
        unsigned p = ps[tid];
        bool active = true;
        for (int u = tid + 1; u < NT_; u++)
            if (ps[u] == p) { active = false; break; }  // last-wins dedup
        if (active) {
            float4 prv = ((const float4*)priors)[p];
            float hw = prv.z * 0.5f, hh = prv.w * 0.5f;
            float qx0 = prv.x - hw, qy0 = prv.y - hh;
            float qx1 = prv.x + hw, qy1 = prv.y + hh;
            float areab = (qx1 - qx0) * (qy1 - qy0);
            unsigned pk = 0u;
            for (int tt = 0; tt < NT_; tt++) {
                float4 tb = trb[tt];
                float iou = iou_fast(tb.x, tb.y, tb.z, tb.w, tra[tt],
                                     qx0, qy0, qx1, qy1, areab);
                unsigned cand = ((__float_as_uint(iou) & 0xFFFFFFFCu) << 2)
                              | (unsigned)(15 - tt);
                pk = (cand > pk) ? cand : pk;
            }
            bool pos0 = (pk >= 0xFC000000u);   // identical rule to kernel1
            int t0 = 15 - (int)(pk & 15u);
            size_t bp = (size_t)b * NP_ + p;
            float2 cxyf = ((const float2*)conf)[bp];
            float dd = cxyf.y - cxyf.x;
            float4 ld = ((const float4*)loc)[bp];

            auto sl1_of = [&](int tt) -> float {
                float4 tb = trb[tt];
                float gcx = ((tb.x + tb.z) * 0.5f - prv.x) / (0.1f * prv.z);
                float gcy = ((tb.y + tb.w) * 0.5f - prv.y) / (0.1f * prv.w);
                float gw = __logf((tb.z - tb.x) / prv.z) * 5.0f;
                float gh = __logf((tb.w - tb.y) / prv.w) * 5.0f;
                float d0 = fabsf(ld.x - gcx), d1 = fabsf(ld.y - gcy);
                float d2 = fabsf(ld.z - gw),  d3 = fabsf(ld.w - gh);
                float s = (d0 < 1.0f) ? 0.5f * d0 * d0 : d0 - 0.5f;
                s += (d1 < 1.0f) ? 0.5f * d1 * d1 : d1 - 0.5f;
                s += (d2 < 1.0f) ? 0.5f * d2 * d2 : d2 - 0.5f;
                s += (d3 < 1.0f) ? 0.5f * d3 * d3 : d3 - 0.5f;
                return s;
            };
            float dll = sl1_of(tid) - (pos0 ? sl1_of(t0) : 0.0f);
            atomicAdd(&s_dll, dll);            // LDS atomic, single wave -> fixed HW order
            if (!pos0) {
                float v = softplus_(dd);       // identical expr to binned value
                int bin = min(HB - 1, (int)(v * HSCALE));
                atomicSub(&hc[bin], 1);
                atomicAdd(&hs[bin], -v);
                atomicAdd(&s_dpc, softplus_(-dd));
                atomicAdd(&s_dnp, 1);
            }
        }
    }
    __syncthreads();

    if (tid < 16) {
        unsigned cacc = 0; float sacc = 0.0f;
        for (int j = 0; j < 64; j++) { cacc += (unsigned)hc[tid * 64 + j]; sacc += hs[tid * 64 + j]; }
        ccnt[tid] = cacc; csm[tid] = sacc;
    }
    __syncthreads();

    if (tid == 0) {
        float sll = s_sll + s_dll;
        float spc = s_spc + s_dpc;
        int n = s_sn + s_dnp;
        int K = 3 * n;
        if (K > NP_ - 1) K = NP_ - 1;
        float tk = 0.0f;
        if (K > 0) {
            unsigned need = (unsigned)K, cum = 0;
            float s = 0.0f;
            int cb = 15;
            for (; cb > 0; --cb) {
                if (cum + ccnt[cb] >= need) break;
                cum += ccnt[cb]; s += csm[cb];
            }
            int bin = cb * 64 + 63;
            for (; bin > cb * 64; --bin) {
                if (cum + (unsigned)hc[bin] >= need) break;
                cum += (unsigned)hc[bin]; s += hs[bin];
            }
            unsigned rem = need - cum;
            int cv = hc[bin];
            float avg = (cv > 0) ? __fdividef(hs[bin], (float)cv) : 0.0f;
            tk = s + (float)rem * avg;
        }
        final_l[b] = sll;
        final_c[b] = spc + tk;
        final_n[b] = n;
        // no fence: kernel boundary orders these stores before lastK
    }
}

// Kernel 3: trivial cross-batch reduce. Ordered by kernel boundary.
__global__ void __launch_bounds__(64) lastK(
    const float* __restrict__ final_l, const float* __restrict__ final_c,
    const int* __restrict__ final_n, float* __restrict__ out)
{
    const int tid = threadIdx.x;
    float lv = 0.0f, cv = 0.0f;
    int nv = 0;
    if (tid < NB_) { lv = final_l[tid]; cv = final_c[tid]; nv = final_n[tid]; }
    for (int off = 32; off > 0; off >>= 1) {
        lv += __shfl_down(lv, off, 64);
        cv += __shfl_down(cv, off, 64);
        nv += __shfl_down(nv, off, 64);
    }
    if (tid == 0) {
        float fn = (float)nv;
        out[0] = lv / fn;
        out[1] = cv / fn;
    }
}

extern "C" void kernel_launch(void* const* d_in, const int* in_sizes, int n_in,
                              void* d_out, int out_size, void* d_ws, size_t ws_size,
                              hipStream_t stream) {
    const float* loc = (const float*)d_in[0];
    const float* conf = (const float*)d_in[1];
    const float* priors = (const float*)d_in[2];
    const float* targets = (const float*)d_in[3];
    float* out = (float*)d_out;

    char* w = (char*)d_ws;
    unsigned short* gcnt = (unsigned short*)w;             // 32*64*1024*2 = 4 MB
    float* gsum = (float*)(w + (4u << 20));                // 32*64*1024*4 = 8 MB
    char* acc = w + (12u << 20);
    unsigned long long* bestPart = (unsigned long long*)acc;        // 256 KB
    float* part_ll = (float*)(acc + 262144);                        // 8 KB
    float* part_pc = (float*)(acc + 270336);                        // 8 KB
    int* part_np   = (int*)(acc + 278528);                          // 8 KB
    float* final_l = (float*)(acc + 286720);                        // 128 B
    float* final_c = (float*)(acc + 286848);                        // 128 B
    int* final_n   = (int*)(acc + 286976);                          // 128 B

    mainK<<<dim3(NBX, NB_), 256, 0, stream>>>(loc, conf, priors, targets,
                                              gcnt, gsum, bestPart,
                                              part_ll, part_pc, part_np);
    finishK<<<NB_, 1024, 0, stream>>>(loc, conf, priors, targets,
                                      gcnt, gsum, bestPart,
                                      part_ll, part_pc, part_np,
                                      final_l, final_c, final_n);
    lastK<<<1, 64, 0, stream>>>(final_l, final_c, final_n, out);
}